// Round 11
// baseline (886.959 us; speedup 1.0000x reference)
//
#include <hip/hip_runtime.h>

typedef _Float16 f16;
typedef _Float16 f16x8 __attribute__((ext_vector_type(8)));
typedef _Float16 f16x4 __attribute__((ext_vector_type(4)));
typedef float f32x4 __attribute__((ext_vector_type(4)));

#define MFMA16(a, b, c) __builtin_amdgcn_mfma_f32_16x16x32_f16((a), (b), (c), 0, 0, 0)
#define CLAMP01(x) __builtin_amdgcn_fmed3f((x), 0.0f, 1.0f)

constexpr int BATCH = 16384;
constexpr int H     = 256;
constexpr int IN    = 784;
constexpr int OUT   = 10;
constexpr int TSTEP = 50;
constexpr int BM    = 64;    // 4 m-tiles of 16 -> grid 256 = 1 block/CU, ONE round
constexpr int NTHR  = 512;   // 8 waves; waves 0-3 update s2 (read s1), 4-7 update s1 (read s2,s0)
constexpr int SROW  = 264;   // f16 row stride (R3-verified)
constexpr int S0ROW = 40;    // f16 stride, s0 tile, K padded 10->32
constexpr int DROW  = 808;   // f16 stride, data staging overlay
constexpr int BXROW = 268;   // f32 stride, x2-bias hand-off buffer (prologue only now)
constexpr int W0TROW= 16;    // f16 stride, W0^T tile
constexpr int EROW  = 268;   // f32 stride, epilogue transpose buffer

// LDS map (f16 units), total 158,976 B <= 160 KiB -> 1 block/CU.
// (R8 lesson: bias must stay on-chip — global scratch re-fetched 789MB/dispatch.)
// R11: bx is now PROLOGUE-ONLY (bias lives in packed-f16 registers in the loop).
constexpr int OFF_S1  = 0;
constexpr int OFF_S2  = OFF_S1 + BM * SROW;      // 16896
constexpr int OFF_S0  = OFF_S2 + BM * SROW;      // 33792
constexpr int OFF_W0N = OFF_S0 + BM * S0ROW;     // 36352
constexpr int OFF_W0T = OFF_W0N + 16 * SROW;     // 40576
constexpr int OFF_B2  = OFF_W0T + H * W0TROW;    // 44672 : f32[256] (pre-halved b2)
constexpr int OFF_BX  = OFF_B2 + 2 * H;          // 45184 : f32[64][268] (pre-halved x2+b4, [m][h])
constexpr int POOL_F16 = OFF_BX + 2 * BM * BXROW; // 79488 f16 = 158,976 B
// Overlays (barrier-separated): data staging [64][808] f16 from 0 (pre-loop);
// epilogue f32 [64][268] from 0 (post-loop).

// Register budget (2 waves/EU -> 256/wave; (NTHR,2) is load-bearing — R2/R7 lessons).
// Persistent: w[4][8]=128 + sm[4][4]=64 + bxr[4][4] f16x4=32 = 224; transients ~20.
// WRITE_SIZE is the spill canary: if it jumps past ~75MB, this overflowed 256.
__global__ __launch_bounds__(NTHR, 2) void ep_step_kernel(
    const float* __restrict__ data, const float* __restrict__ s0_in,
    const float* __restrict__ s1_in, const float* __restrict__ s2_in,
    const float* __restrict__ W0, const float* __restrict__ b0,
    const float* __restrict__ W2, const float* __restrict__ b2,
    const float* __restrict__ W4, const float* __restrict__ b4,
    float* __restrict__ out)
{
    __shared__ __align__(16) f16 pool[POOL_F16];

    const int tid  = threadIdx.x;
    const int wave = tid >> 6;
    const int lane = tid & 63;
    const int q    = lane >> 4;   // quad 0..3
    const int l16  = lane & 15;
    const int m0   = blockIdx.x * BM;
    const bool isS1 = (wave >= 4);     // role: waves 4-7 update s1; 0-3 update s2
    const int  dmt  = wave & 3;        // s2 waves: m-tile whose s0-update this wave carries
    const int h0   = (wave & 3) * 64;  // 64-row h slab in the main loop (4 tiles of 16)
    const int hx   = wave * 32;        // 32-row h slab for the x2 prologue

    float* const bx  = (float*)&pool[OFF_BX];
    float* const b2l = (float*)&pool[OFF_B2];

    // ---- phase 1: stage rho(data)->f16 into LDS overlay ---------------------------------------
    for (int i = tid; i < BM * (DROW / 4); i += NTHR) {
        int m  = i / (DROW / 4);
        int k4 = (i % (DROW / 4)) * 4;
        f16x4 p = {(f16)0.f, (f16)0.f, (f16)0.f, (f16)0.f};
        if (k4 < IN) {
            f32x4 v = *(const f32x4*)(data + (size_t)(m0 + m) * IN + k4);
            #pragma unroll
            for (int j = 0; j < 4; ++j) p[j] = (f16)CLAMP01(v[j]);
        }
        *(f16x4*)&pool[m * DROW + k4] = p;
    }
    __syncthreads();

    // ---- phase 2: x2 = rho(data) @ W4^T (C[h][m]) -- all 8 waves, 32h x 64m each --------------
    f32x4 x2a[2][4] = {};
    for (int kk = 0; kk < 25; ++kk) {
        int kb = kk * 32 + q * 8;
        f16x8 bd[4];
        #pragma unroll
        for (int mt = 0; mt < 4; ++mt)
            bd[mt] = *(const f16x8*)&pool[(mt * 16 + l16) * DROW + kb];
        #pragma unroll
        for (int ht = 0; ht < 2; ++ht) {
            int h = hx + ht * 16 + l16;
            f16x8 wa4;
            if (kk < 24) {
                f32x4 u0 = *(const f32x4*)(W4 + (size_t)h * IN + kb);
                f32x4 u1 = *(const f32x4*)(W4 + (size_t)h * IN + kb + 4);
                #pragma unroll
                for (int j = 0; j < 4; ++j) { wa4[j] = (f16)u0[j]; wa4[j + 4] = (f16)u1[j]; }
            } else {
                #pragma unroll
                for (int j = 0; j < 8; ++j) {
                    int k = kb + j;
                    wa4[j] = (k < IN) ? (f16)W4[(size_t)h * IN + k] : (f16)0.f;
                }
            }
            #pragma unroll
            for (int mt = 0; mt < 4; ++mt)
                x2a[ht][mt] = MFMA16(wa4, bd[mt], x2a[ht][mt]);
        }
    }
    __syncthreads();  // staging overlay dead

    // ---- phase 3: persistent small LDS tiles (all overlap the dead staging region) ------------
    // bias hand-off buffer, TRANSPOSED [m][h], pre-halved: 0.5*(x2+b4)
    #pragma unroll
    for (int ht = 0; ht < 2; ++ht)
        #pragma unroll
        for (int mt = 0; mt < 4; ++mt) {
            f32x4 v = x2a[ht][mt];
            #pragma unroll
            for (int r = 0; r < 4; ++r) v[r] = 0.5f * (v[r] + b4[hx + ht * 16 + q * 4 + r]);
            *(f32x4*)&bx[(mt * 16 + l16) * BXROW + hx + ht * 16 + q * 4] = v;
        }
    for (int i = tid; i < 16 * SROW; i += NTHR) {
        int o = i / SROW, k = i % SROW;
        pool[OFF_W0N + i] = (o < OUT && k < H) ? (f16)W0[o * H + k] : (f16)0.f;
    }
    for (int i = tid; i < H * W0TROW; i += NTHR) {
        int h = i / W0TROW, o = i % W0TROW;
        pool[OFF_W0T + i] = (o < OUT) ? (f16)W0[o * H + h] : (f16)0.f;
    }
    for (int i = tid; i < H; i += NTHR) b2l[i] = 0.5f * b2[i];
    for (int i = tid; i < BM * S0ROW; i += NTHR) pool[OFF_S0 + i] = (f16)0.f;
    __syncthreads();

    // ---- phase 4: persistent register weights + bias-in-regs + fp32 masters -------------------
    asm volatile("" ::: "memory");  // keep the big W2 streams from hoisting into the prologue
    f16x8 w[4][8];
    f16x4 bxr[4][4];  // s2 waves ONLY: bias 0.5*(x2+b4) packed f16 (R11: was LDS reads/step)
    if (!isS1) {
        // s2-update: o2 = s1 @ W2  ->  A'[h][k] = W2[k][h]
        #pragma unroll
        for (int ht = 0; ht < 4; ++ht) {
            int h = h0 + ht * 16 + l16;
            #pragma unroll
            for (int kk = 0; kk < 8; ++kk) {
                int kb = kk * 32 + q * 8;
                f16x8 wa;
                #pragma unroll
                for (int j = 0; j < 8; ++j) wa[j] = (f16)W2[(kb + j) * H + h];
                w[ht][kk] = wa;
            }
        }
        // one-time bias pickup from the hand-off buffer into packed f16 registers
        #pragma unroll
        for (int ht = 0; ht < 4; ++ht)
            #pragma unroll
            for (int mt = 0; mt < 4; ++mt) {
                f32x4 bv = *(const f32x4*)&bx[(mt * 16 + l16) * BXROW + h0 + ht * 16 + q * 4];
                #pragma unroll
                for (int r = 0; r < 4; ++r) bxr[ht][mt][r] = (f16)bv[r];
            }
    } else {
        // s1-update: o1 = s2 @ W2^T  ->  A'[h][k] = W2[h][k]
        #pragma unroll
        for (int ht = 0; ht < 4; ++ht) {
            int h = h0 + ht * 16 + l16;
            #pragma unroll
            for (int kk = 0; kk < 8; ++kk) {
                int kb = kk * 32 + q * 8;
                f32x4 u0 = *(const f32x4*)(W2 + h * H + kb);
                f32x4 u1 = *(const f32x4*)(W2 + h * H + kb + 4);
                f16x8 wb;
                #pragma unroll
                for (int j = 0; j < 4; ++j) { wb[j] = (f16)u0[j]; wb[j + 4] = (f16)u1[j]; }
                w[ht][kk] = wb;
            }
        }
    }
    f32x4 sm[4][4];   // master state = in-place MFMA accumulator (C layout: h=q*4+r, m=mt*16+l16)
    const float* sin_p = isS1 ? s1_in : s2_in;
    #pragma unroll
    for (int ht = 0; ht < 4; ++ht)
        #pragma unroll
        for (int mt = 0; mt < 4; ++mt)
            sm[ht][mt] = *(const f32x4*)&sin_p[(size_t)(m0 + mt * 16 + l16) * H + h0 + ht * 16 + q * 4];
    f32x4 s0m = {0.f, 0.f, 0.f, 0.f}, b0h = {0.f, 0.f, 0.f, 0.f};
    if (!isS1) {
        #pragma unroll
        for (int r = 0; r < 4; ++r) {
            int o = q * 4 + r;
            if (o < OUT) {
                s0m[r] = s0_in[(size_t)(m0 + dmt * 16 + l16) * OUT + o];
                b0h[r] = 0.5f * b0[o];
            }
        }
    }

    // conflict-free b64 writeback of this wave's OWN state (+ s0 slice for s2 waves)
    auto writeback = [&]() {
        f16* ws = &pool[isS1 ? OFF_S1 : OFF_S2];
        #pragma unroll
        for (int ht = 0; ht < 4; ++ht) {
            int hb = h0 + ht * 16 + q * 4;
            #pragma unroll
            for (int mt = 0; mt < 4; ++mt) {
                f16x4 p;
                #pragma unroll
                for (int r = 0; r < 4; ++r) p[r] = (f16)sm[ht][mt][r];
                *(f16x4*)&ws[(mt * 16 + l16) * SROW + hb] = p;
            }
        }
        if (!isS1) {
            int ob = q * 4;
            if (ob < OUT) {  // q=0,1,2 ; o=10,11 padded with zeros; o>=12 zeroed once in phase 3
                f16x4 p;
                #pragma unroll
                for (int r = 0; r < 4; ++r) p[r] = (ob + r < OUT) ? (f16)s0m[r] : (f16)0.f;
                *(f16x4*)&pool[OFF_S0 + (dmt * 16 + l16) * S0ROW + ob] = p;
            }
        }
    };

    auto compute = [&]() {
        const f16* rs = &pool[isS1 ? OFF_S2 : OFF_S1];  // read the OPPOSITE state, full K
        if (isS1) {
            // s0@W0 term FIRST so its 32 staging regs are dead before the kk-loop
            #pragma unroll
            for (int ht = 0; ht < 4; ++ht) {
                f16x8 w0cv = {};
                if (q < 2)
                    w0cv = *(const f16x8*)&pool[OFF_W0T + (h0 + ht * 16 + l16) * W0TROW + q * 8];
                #pragma unroll
                for (int mt = 0; mt < 4; ++mt) {
                    f16x8 b0v = *(const f16x8*)&pool[OFF_S0 + (mt * 16 + l16) * S0ROW + q * 8];
                    sm[ht][mt] = MFMA16(w0cv, b0v, sm[ht][mt]);
                }
            }
        }
        #pragma unroll
        for (int kk = 0; kk < 8; ++kk) {
            int kb = kk * 32 + q * 8;
            f16x8 b[4];
            #pragma unroll
            for (int mt = 0; mt < 4; ++mt)
                b[mt] = *(const f16x8*)&rs[(mt * 16 + l16) * SROW + kb];
            __builtin_amdgcn_s_setprio(1);
            #pragma unroll
            for (int ht = 0; ht < 4; ++ht)
                #pragma unroll
                for (int mt = 0; mt < 4; ++mt)
                    sm[ht][mt] = MFMA16(w[ht][kk], b[mt], sm[ht][mt]);
            if (!isS1) {
                // s0-update rides on this wave's own m-tile; mt==dmt is wave-uniform (scalar branch)
                f16x8 a0 = *(const f16x8*)&pool[OFF_W0N + l16 * SROW + kb];
                #pragma unroll
                for (int mt = 0; mt < 4; ++mt)
                    if (mt == dmt) s0m = MFMA16(a0, b[mt], s0m);
            }
            __builtin_amdgcn_s_setprio(0);
        }
        // bias + clamp. s2 waves: bias from REGISTERS (R11) — no LDS reads in the tail.
        if (isS1) {
            #pragma unroll
            for (int ht = 0; ht < 4; ++ht) {
                f32x4 bhv = *(const f32x4*)&b2l[h0 + ht * 16 + q * 4];  // broadcast read
                #pragma unroll
                for (int mt = 0; mt < 4; ++mt)
                    #pragma unroll
                    for (int r = 0; r < 4; ++r)
                        sm[ht][mt][r] = CLAMP01(fmaf(0.5f, sm[ht][mt][r], bhv[r]));
            }
        } else {
            #pragma unroll
            for (int ht = 0; ht < 4; ++ht)
                #pragma unroll
                for (int mt = 0; mt < 4; ++mt)
                    #pragma unroll
                    for (int r = 0; r < 4; ++r)
                        sm[ht][mt][r] = CLAMP01(fmaf(0.5f, sm[ht][mt][r], (float)bxr[ht][mt][r]));
            #pragma unroll
            for (int r = 0; r < 4; ++r)
                s0m[r] = CLAMP01(fmaf(0.5f, s0m[r], b0h[r]));
        }
    };

    writeback();          // initial states into LDS
    __syncthreads();

    // ---- main loop: single-buffered, 2 barriers/step ------------------------------------------
    #pragma unroll 1
    for (int t = 0; t < TSTEP; ++t) {
        compute();        // reads only (opposite state + s0), accumulates in regs
        __syncthreads();  // all reads of old state done
        writeback();      // write own state in place
        __syncthreads();  // new state visible
    }

    // ---- epilogue: s0 direct; s1/s2 via coalescing LDS transpose (overlay) --------------------
    if (!isS1) {
        #pragma unroll
        for (int r = 0; r < 4; ++r) {
            int o = q * 4 + r;
            if (o < OUT) out[(size_t)(m0 + dmt * 16 + l16) * OUT + o] = s0m[r];
        }
    }
    float* xf = (float*)pool;  // [64][EROW] f32 overlay
    float* o1p = out + (size_t)BATCH * OUT;
    float* o2p = o1p + (size_t)BATCH * H;
    if (isS1) {
        #pragma unroll
        for (int ht = 0; ht < 4; ++ht)
            #pragma unroll
            for (int mt = 0; mt < 4; ++mt)
                *(f32x4*)&xf[(mt * 16 + l16) * EROW + h0 + ht * 16 + q * 4] = sm[ht][mt];
    }
    __syncthreads();
    for (int i = tid; i < BM * H / 4; i += NTHR) {
        int m = i >> 6, c = (i & 63) * 4;
        f32x4 v = *(const f32x4*)&xf[m * EROW + c];
        *(f32x4*)&o1p[(size_t)(m0 + m) * H + c] = v;
    }
    __syncthreads();
    if (!isS1) {
        #pragma unroll
        for (int ht = 0; ht < 4; ++ht)
            #pragma unroll
            for (int mt = 0; mt < 4; ++mt)
                *(f32x4*)&xf[(mt * 16 + l16) * EROW + h0 + ht * 16 + q * 4] = sm[ht][mt];
    }
    __syncthreads();
    for (int i = tid; i < BM * H / 4; i += NTHR) {
        int m = i >> 6, c = (i & 63) * 4;
        f32x4 v = *(const f32x4*)&xf[m * EROW + c];
        *(f32x4*)&o2p[(size_t)(m0 + m) * H + c] = v;
    }
}

extern "C" void kernel_launch(void* const* d_in, const int* in_sizes, int n_in,
                              void* d_out, int out_size, void* d_ws, size_t ws_size,
                              hipStream_t stream) {
    const float* data  = (const float*)d_in[0];
    const float* s0_in = (const float*)d_in[1];
    const float* s1_in = (const float*)d_in[2];
    const float* s2_in = (const float*)d_in[3];
    const float* W0    = (const float*)d_in[4];
    const float* b0    = (const float*)d_in[5];
    const float* W2    = (const float*)d_in[6];
    const float* b2    = (const float*)d_in[7];
    const float* W4    = (const float*)d_in[8];
    const float* b4    = (const float*)d_in[9];
    float* out = (float*)d_out;

    ep_step_kernel<<<BATCH / BM, NTHR, 0, stream>>>(
        data, s0_in, s1_in, s2_in, W0, b0, W2, b2, W4, b4, out);
}

// Round 12
// 342.687 us; speedup vs baseline: 2.5883x; 2.5883x over previous
//
#include <hip/hip_runtime.h>

typedef _Float16 f16;
typedef _Float16 f16x8 __attribute__((ext_vector_type(8)));
typedef _Float16 f16x4 __attribute__((ext_vector_type(4)));
typedef float f32x4 __attribute__((ext_vector_type(4)));

#define MFMA16(a, b, c) __builtin_amdgcn_mfma_f32_16x16x32_f16((a), (b), (c), 0, 0, 0)
#define CLAMP01(x) __builtin_amdgcn_fmed3f((x), 0.0f, 1.0f)

constexpr int BATCH = 16384;
constexpr int H     = 256;
constexpr int IN    = 784;
constexpr int OUT   = 10;
constexpr int TSTEP = 50;
constexpr int BM    = 64;    // 4 m-tiles of 16 -> grid 256 = 1 block/CU, ONE round
constexpr int NTHR  = 512;   // 8 waves; waves 0-3 update s2 (read s1), 4-7 update s1 (read s2,s0)
constexpr int SROW  = 264;   // f16 row stride (R3-verified)
constexpr int S0ROW = 40;    // f16 stride, s0 tile, K padded 10->32
constexpr int DROW  = 808;   // f16 stride, data staging overlay
constexpr int BXROW = 268;   // f32 stride, x2-bias buffer
constexpr int W0TROW= 16;    // f16 stride, W0^T tile
constexpr int EROW  = 268;   // f32 stride, epilogue transpose buffer

// LDS map (f16 units), total 158,976 B <= 160 KiB -> 1 block/CU.
// (R8: bias must stay in LDS. R11: bias must NOT move to registers — 32 extra
// persistent regs overflow the 256 unified budget and spill the weights.)
constexpr int OFF_S1  = 0;
constexpr int OFF_S2  = OFF_S1 + BM * SROW;      // 16896
constexpr int OFF_S0  = OFF_S2 + BM * SROW;      // 33792
constexpr int OFF_W0N = OFF_S0 + BM * S0ROW;     // 36352
constexpr int OFF_W0T = OFF_W0N + 16 * SROW;     // 40576
constexpr int OFF_B2  = OFF_W0T + H * W0TROW;    // 44672 : f32[256] (pre-halved b2)
constexpr int OFF_BX  = OFF_B2 + 2 * H;          // 45184 : f32[64][268] (pre-halved x2+b4, [m][h])
constexpr int POOL_F16 = OFF_BX + 2 * BM * BXROW; // 79488 f16 = 158,976 B
// Overlays (barrier-separated): data staging [64][808] f16 from 0 (pre-loop);
// epilogue f32 [64][268] from 0 (post-loop).

// Register budget (2 waves/EU -> 256/wave; (NTHR,2) load-bearing).
// Persistent ceiling (R11 lesson): w[4][8]=128 + sm[4][4]=64 = 192. Transients only.
// R12: kk-loops are BRANCH-FREE straight-line regions so the compiler can hoist
// next-kk ds_reads across MFMA clusters (counted lgkmcnt pipelining, m97-style).
__global__ __launch_bounds__(NTHR, 2) void ep_step_kernel(
    const float* __restrict__ data, const float* __restrict__ s0_in,
    const float* __restrict__ s1_in, const float* __restrict__ s2_in,
    const float* __restrict__ W0, const float* __restrict__ b0,
    const float* __restrict__ W2, const float* __restrict__ b2,
    const float* __restrict__ W4, const float* __restrict__ b4,
    float* __restrict__ out)
{
    __shared__ __align__(16) f16 pool[POOL_F16];

    const int tid  = threadIdx.x;
    const int wave = tid >> 6;
    const int lane = tid & 63;
    const int q    = lane >> 4;   // quad 0..3
    const int l16  = lane & 15;
    const int m0   = blockIdx.x * BM;
    const bool isS1 = (wave >= 4);     // role: waves 4-7 update s1; 0-3 update s2
    const int  dmt  = wave & 3;        // s2 waves: m-tile whose s0-update this wave carries
    const int h0   = (wave & 3) * 64;  // 64-row h slab in the main loop (4 tiles of 16)
    const int hx   = wave * 32;        // 32-row h slab for the x2 prologue

    float* const bx  = (float*)&pool[OFF_BX];
    float* const b2l = (float*)&pool[OFF_B2];

    // ---- phase 1: stage rho(data)->f16 into LDS overlay ---------------------------------------
    for (int i = tid; i < BM * (DROW / 4); i += NTHR) {
        int m  = i / (DROW / 4);
        int k4 = (i % (DROW / 4)) * 4;
        f16x4 p = {(f16)0.f, (f16)0.f, (f16)0.f, (f16)0.f};
        if (k4 < IN) {
            f32x4 v = *(const f32x4*)(data + (size_t)(m0 + m) * IN + k4);
            #pragma unroll
            for (int j = 0; j < 4; ++j) p[j] = (f16)CLAMP01(v[j]);
        }
        *(f16x4*)&pool[m * DROW + k4] = p;
    }
    __syncthreads();

    // ---- phase 2: x2 = rho(data) @ W4^T (C[h][m]) -- all 8 waves, 32h x 64m each --------------
    f32x4 x2a[2][4] = {};
    for (int kk = 0; kk < 25; ++kk) {
        int kb = kk * 32 + q * 8;
        f16x8 bd[4];
        #pragma unroll
        for (int mt = 0; mt < 4; ++mt)
            bd[mt] = *(const f16x8*)&pool[(mt * 16 + l16) * DROW + kb];
        #pragma unroll
        for (int ht = 0; ht < 2; ++ht) {
            int h = hx + ht * 16 + l16;
            f16x8 wa4;
            if (kk < 24) {
                f32x4 u0 = *(const f32x4*)(W4 + (size_t)h * IN + kb);
                f32x4 u1 = *(const f32x4*)(W4 + (size_t)h * IN + kb + 4);
                #pragma unroll
                for (int j = 0; j < 4; ++j) { wa4[j] = (f16)u0[j]; wa4[j + 4] = (f16)u1[j]; }
            } else {
                #pragma unroll
                for (int j = 0; j < 8; ++j) {
                    int k = kb + j;
                    wa4[j] = (k < IN) ? (f16)W4[(size_t)h * IN + k] : (f16)0.f;
                }
            }
            #pragma unroll
            for (int mt = 0; mt < 4; ++mt)
                x2a[ht][mt] = MFMA16(wa4, bd[mt], x2a[ht][mt]);
        }
    }
    __syncthreads();  // staging overlay dead

    // ---- phase 3: persistent small LDS tiles (all overlap the dead staging region) ------------
    // bias buffer, TRANSPOSED [m][h], pre-halved: 0.5*(x2+b4)
    #pragma unroll
    for (int ht = 0; ht < 2; ++ht)
        #pragma unroll
        for (int mt = 0; mt < 4; ++mt) {
            f32x4 v = x2a[ht][mt];
            #pragma unroll
            for (int r = 0; r < 4; ++r) v[r] = 0.5f * (v[r] + b4[hx + ht * 16 + q * 4 + r]);
            *(f32x4*)&bx[(mt * 16 + l16) * BXROW + hx + ht * 16 + q * 4] = v;
        }
    for (int i = tid; i < 16 * SROW; i += NTHR) {
        int o = i / SROW, k = i % SROW;
        pool[OFF_W0N + i] = (o < OUT && k < H) ? (f16)W0[o * H + k] : (f16)0.f;
    }
    for (int i = tid; i < H * W0TROW; i += NTHR) {
        int h = i / W0TROW, o = i % W0TROW;
        pool[OFF_W0T + i] = (o < OUT) ? (f16)W0[o * H + h] : (f16)0.f;
    }
    for (int i = tid; i < H; i += NTHR) b2l[i] = 0.5f * b2[i];
    for (int i = tid; i < BM * S0ROW; i += NTHR) pool[OFF_S0 + i] = (f16)0.f;
    __syncthreads();

    // ---- phase 4: persistent register weights + fp32 masters ----------------------------------
    asm volatile("" ::: "memory");  // keep the big W2 streams from hoisting into the prologue
    f16x8 w[4][8];
    if (!isS1) {
        // s2-update: o2 = s1 @ W2  ->  A'[h][k] = W2[k][h]
        #pragma unroll
        for (int ht = 0; ht < 4; ++ht) {
            int h = h0 + ht * 16 + l16;
            #pragma unroll
            for (int kk = 0; kk < 8; ++kk) {
                int kb = kk * 32 + q * 8;
                f16x8 wa;
                #pragma unroll
                for (int j = 0; j < 8; ++j) wa[j] = (f16)W2[(kb + j) * H + h];
                w[ht][kk] = wa;
            }
        }
    } else {
        // s1-update: o1 = s2 @ W2^T  ->  A'[h][k] = W2[h][k]
        #pragma unroll
        for (int ht = 0; ht < 4; ++ht) {
            int h = h0 + ht * 16 + l16;
            #pragma unroll
            for (int kk = 0; kk < 8; ++kk) {
                int kb = kk * 32 + q * 8;
                f32x4 u0 = *(const f32x4*)(W2 + h * H + kb);
                f32x4 u1 = *(const f32x4*)(W2 + h * H + kb + 4);
                f16x8 wb;
                #pragma unroll
                for (int j = 0; j < 4; ++j) { wb[j] = (f16)u0[j]; wb[j + 4] = (f16)u1[j]; }
                w[ht][kk] = wb;
            }
        }
    }
    f32x4 sm[4][4];   // master state = in-place MFMA accumulator (C layout: h=q*4+r, m=mt*16+l16)
    const float* sin_p = isS1 ? s1_in : s2_in;
    #pragma unroll
    for (int ht = 0; ht < 4; ++ht)
        #pragma unroll
        for (int mt = 0; mt < 4; ++mt)
            sm[ht][mt] = *(const f32x4*)&sin_p[(size_t)(m0 + mt * 16 + l16) * H + h0 + ht * 16 + q * 4];
    f32x4 s0m = {0.f, 0.f, 0.f, 0.f}, b0h = {0.f, 0.f, 0.f, 0.f};
    if (!isS1) {
        #pragma unroll
        for (int r = 0; r < 4; ++r) {
            int o = q * 4 + r;
            if (o < OUT) {
                s0m[r] = s0_in[(size_t)(m0 + dmt * 16 + l16) * OUT + o];
                b0h[r] = 0.5f * b0[o];
            }
        }
    }

    // conflict-free b64 writeback of this wave's OWN state (+ s0 slice for s2 waves)
    auto writeback = [&]() {
        f16* ws = &pool[isS1 ? OFF_S1 : OFF_S2];
        #pragma unroll
        for (int ht = 0; ht < 4; ++ht) {
            int hb = h0 + ht * 16 + q * 4;
            #pragma unroll
            for (int mt = 0; mt < 4; ++mt) {
                f16x4 p;
                #pragma unroll
                for (int r = 0; r < 4; ++r) p[r] = (f16)sm[ht][mt][r];
                *(f16x4*)&ws[(mt * 16 + l16) * SROW + hb] = p;
            }
        }
        if (!isS1) {
            int ob = q * 4;
            if (ob < OUT) {  // q=0,1,2 ; o=10,11 padded with zeros; o>=12 zeroed once in phase 3
                f16x4 p;
                #pragma unroll
                for (int r = 0; r < 4; ++r) p[r] = (ob + r < OUT) ? (f16)s0m[r] : (f16)0.f;
                *(f16x4*)&pool[OFF_S0 + (dmt * 16 + l16) * S0ROW + ob] = p;
            }
        }
    };

    // R12: role-split compute — each role's kk-loop is one BRANCH-FREE straight-line
    // region so the compiler can software-pipeline ds_reads across MFMA clusters.
    auto compute = [&]() {
        if (isS1) {
            const f16* rs = &pool[OFF_S2];
            // s0@W0 term first (staging regs dead before the kk-loop)
            #pragma unroll
            for (int ht = 0; ht < 4; ++ht) {
                f16x8 w0cv = {};
                if (q < 2)
                    w0cv = *(const f16x8*)&pool[OFF_W0T + (h0 + ht * 16 + l16) * W0TROW + q * 8];
                #pragma unroll
                for (int mt = 0; mt < 4; ++mt) {
                    f16x8 b0v = *(const f16x8*)&pool[OFF_S0 + (mt * 16 + l16) * S0ROW + q * 8];
                    sm[ht][mt] = MFMA16(w0cv, b0v, sm[ht][mt]);
                }
            }
            #pragma unroll
            for (int kk = 0; kk < 8; ++kk) {        // branch-free body
                int kb = kk * 32 + q * 8;
                f16x8 b[4];
                #pragma unroll
                for (int mt = 0; mt < 4; ++mt)
                    b[mt] = *(const f16x8*)&rs[(mt * 16 + l16) * SROW + kb];
                #pragma unroll
                for (int ht = 0; ht < 4; ++ht)
                    #pragma unroll
                    for (int mt = 0; mt < 4; ++mt)
                        sm[ht][mt] = MFMA16(w[ht][kk], b[mt], sm[ht][mt]);
            }
            #pragma unroll
            for (int ht = 0; ht < 4; ++ht) {
                f32x4 bhv = *(const f32x4*)&b2l[h0 + ht * 16 + q * 4];  // broadcast read
                #pragma unroll
                for (int mt = 0; mt < 4; ++mt)
                    #pragma unroll
                    for (int r = 0; r < 4; ++r)
                        sm[ht][mt][r] = CLAMP01(fmaf(0.5f, sm[ht][mt][r], bhv[r]));
            }
        } else {
            const f16* rs = &pool[OFF_S1];
            const f16* rd = &pool[OFF_S1 + (dmt * 16 + l16) * SROW];  // duty fragment row (wave-const base)
            #pragma unroll
            for (int kk = 0; kk < 8; ++kk) {        // branch-free body (branchless duty)
                int kb = kk * 32 + q * 8;
                f16x8 b[4];
                #pragma unroll
                for (int mt = 0; mt < 4; ++mt)
                    b[mt] = *(const f16x8*)&rs[(mt * 16 + l16) * SROW + kb];
                f16x8 a0 = *(const f16x8*)&pool[OFF_W0N + l16 * SROW + kb];
                f16x8 bd = *(const f16x8*)&rd[kb];  // == b[dmt], re-read (no branch, no dyn index)
                #pragma unroll
                for (int ht = 0; ht < 4; ++ht)
                    #pragma unroll
                    for (int mt = 0; mt < 4; ++mt)
                        sm[ht][mt] = MFMA16(w[ht][kk], b[mt], sm[ht][mt]);
                s0m = MFMA16(a0, bd, s0m);
            }
            #pragma unroll
            for (int ht = 0; ht < 4; ++ht)
                #pragma unroll
                for (int mt = 0; mt < 4; ++mt) {
                    f32x4 bv = *(const f32x4*)&bx[(mt * 16 + l16) * BXROW + h0 + ht * 16 + q * 4];
                    #pragma unroll
                    for (int r = 0; r < 4; ++r)
                        sm[ht][mt][r] = CLAMP01(fmaf(0.5f, sm[ht][mt][r], bv[r]));
                }
            #pragma unroll
            for (int r = 0; r < 4; ++r)
                s0m[r] = CLAMP01(fmaf(0.5f, s0m[r], b0h[r]));
        }
    };

    writeback();          // initial states into LDS
    __syncthreads();

    // ---- main loop: single-buffered, 2 barriers/step ------------------------------------------
    #pragma unroll 1
    for (int t = 0; t < TSTEP; ++t) {
        compute();        // reads only (opposite state + s0 + bias), accumulates in regs
        __syncthreads();  // all reads of old state done
        writeback();      // write own state in place
        __syncthreads();  // new state visible
    }

    // ---- epilogue: s0 direct; s1/s2 via coalescing LDS transpose (overlay) --------------------
    if (!isS1) {
        #pragma unroll
        for (int r = 0; r < 4; ++r) {
            int o = q * 4 + r;
            if (o < OUT) out[(size_t)(m0 + dmt * 16 + l16) * OUT + o] = s0m[r];
        }
    }
    float* xf = (float*)pool;  // [64][EROW] f32 overlay
    float* o1p = out + (size_t)BATCH * OUT;
    float* o2p = o1p + (size_t)BATCH * H;
    if (isS1) {
        #pragma unroll
        for (int ht = 0; ht < 4; ++ht)
            #pragma unroll
            for (int mt = 0; mt < 4; ++mt)
                *(f32x4*)&xf[(mt * 16 + l16) * EROW + h0 + ht * 16 + q * 4] = sm[ht][mt];
    }
    __syncthreads();
    for (int i = tid; i < BM * H / 4; i += NTHR) {
        int m = i >> 6, c = (i & 63) * 4;
        f32x4 v = *(const f32x4*)&xf[m * EROW + c];
        *(f32x4*)&o1p[(size_t)(m0 + m) * H + c] = v;
    }
    __syncthreads();
    if (!isS1) {
        #pragma unroll
        for (int ht = 0; ht < 4; ++ht)
            #pragma unroll
            for (int mt = 0; mt < 4; ++mt)
                *(f32x4*)&xf[(mt * 16 + l16) * EROW + h0 + ht * 16 + q * 4] = sm[ht][mt];
    }
    __syncthreads();
    for (int i = tid; i < BM * H / 4; i += NTHR) {
        int m = i >> 6, c = (i & 63) * 4;
        f32x4 v = *(const f32x4*)&xf[m * EROW + c];
        *(f32x4*)&o2p[(size_t)(m0 + m) * H + c] = v;
    }
}

extern "C" void kernel_launch(void* const* d_in, const int* in_sizes, int n_in,
                              void* d_out, int out_size, void* d_ws, size_t ws_size,
                              hipStream_t stream) {
    const float* data  = (const float*)d_in[0];
    const float* s0_in = (const float*)d_in[1];
    const float* s1_in = (const float*)d_in[2];
    const float* s2_in = (const float*)d_in[3];
    const float* W0    = (const float*)d_in[4];
    const float* b0    = (const float*)d_in[5];
    const float* W2    = (const float*)d_in[6];
    const float* b2    = (const float*)d_in[7];
    const float* W4    = (const float*)d_in[8];
    const float* b4    = (const float*)d_in[9];
    float* out = (float*)d_out;

    ep_step_kernel<<<BATCH / BM, NTHR, 0, stream>>>(
        data, s0_in, s1_in, s2_in, W0, b0, W2, b2, W4, b4, out);
}